// Round 8
// baseline (229.244 us; speedup 1.0000x reference)
//
#include <hip/hip_runtime.h>
#include <math.h>

#define B_   2
#define S_   1024
#define HID_ 2048
#define HQ_  32
#define HKV_ 8
#define HD_  64
#define NQKV 3072   // HID + 2*HKV*HD

#define PCHUNK 2097152   // split-attn partial-O chunk stride (fp32 elems)
#define QSC   (0.125f * 1.44269504089f)   // RoPE-Q scale incl. log2(e) for exp2-domain softmax
#define DEFER_THR 11.54f                  // defer-max threshold in log2 units (= 8 nats, r5 semantics)

using short8  = __attribute__((ext_vector_type(8))) short;
using floatx4 = __attribute__((ext_vector_type(4))) float;

__device__ __forceinline__ unsigned short f2bf(float x) {
    unsigned int u = __builtin_bit_cast(unsigned int, x);
    u += 0x7FFFu + ((u >> 16) & 1u);
    return (unsigned short)(u >> 16);
}
__device__ __forceinline__ float bf2f(unsigned short u) {
    return __builtin_bit_cast(float, (unsigned int)u << 16);
}

__device__ __forceinline__ void gl_lds16(const unsigned short* g, unsigned short* l) {
    __builtin_amdgcn_global_load_lds(
        (const __attribute__((address_space(1))) void*)g,
        (__attribute__((address_space(3))) void*)l, 16, 0, 0);
}

// ---------------------------------------------------------------------------
// QKV GEMM, SPLIT-K=2 (768 blocks = 3/CU). 128x128 tile, BK=64, XOR-swizzled
// LDS. XCD-aware block swizzle: 768%8==0 -> bijective chunked remap.
// ---------------------------------------------------------------------------
__global__ __launch_bounds__(256) void gemm_qkv(const unsigned short* __restrict__ A,
                                                const unsigned short* __restrict__ Bt,
                                                unsigned short* __restrict__ Qp,
                                                unsigned short* __restrict__ KVp) {
    __shared__ __align__(16) unsigned short As[128 * 64];
    __shared__ __align__(16) unsigned short Bs[128 * 64];

    int bid = (blockIdx.x & 7) * 96 + (blockIdx.x >> 3);   // XCD chunked swizzle
    int m0, n0, z, Nw, nc0;
    unsigned short* C;
    if (bid < 512) {
        n0 = (bid & 15) * 128; m0 = ((bid >> 4) & 15) * 128; z = bid >> 8;
        C = Qp + (size_t)z * 2048 * 2048; Nw = 2048; nc0 = n0;
    } else {
        bid -= 512;
        n0 = 2048 + (bid & 7) * 128; m0 = ((bid >> 3) & 15) * 128; z = bid >> 7;
        C = KVp + (size_t)z * 2048 * 1024; Nw = 1024; nc0 = n0 - 2048;
    }
    const int kbase = z * 1024;

    const int tid  = threadIdx.x;
    const int w    = tid >> 6;
    const int lane = tid & 63;
    const int col  = lane & 15;
    const int quad = lane >> 4;
    const int wm = (w >> 1) * 64;
    const int wn = (w & 1) * 64;

    const int srow = lane >> 3;
    const int scol = ((lane & 7) ^ srow) * 8;
    const unsigned short* Ag = A  + (size_t)(m0 + w * 32 + srow) * HID_ + scol;
    const unsigned short* Bg = Bt + (size_t)(n0 + w * 32 + srow) * HID_ + scol;

    floatx4 acc[4][4] = {};

    for (int k0 = kbase; k0 < kbase + 1024; k0 += 64) {
#pragma unroll
        for (int c = 0; c < 4; ++c) {
            gl_lds16(Ag + (size_t)(8 * c) * HID_ + k0, &As[(w * 32 + 8 * c) * 64]);
            gl_lds16(Bg + (size_t)(8 * c) * HID_ + k0, &Bs[(w * 32 + 8 * c) * 64]);
        }
        __syncthreads();

#pragma unroll
        for (int hh = 0; hh < 2; ++hh) {
            short8 af[4], bfr[4];
#pragma unroll
            for (int i = 0; i < 4; ++i)
                af[i] = *(const short8*)&As[(wm + i * 16 + col) * 64
                                            + (((hh * 4 + quad) ^ (col & 7)) << 3)];
#pragma unroll
            for (int j = 0; j < 4; ++j)
                bfr[j] = *(const short8*)&Bs[(wn + j * 16 + col) * 64
                                             + (((hh * 4 + quad) ^ (col & 7)) << 3)];
#pragma unroll
            for (int i = 0; i < 4; ++i)
#pragma unroll
                for (int j = 0; j < 4; ++j)
                    acc[i][j] = __builtin_amdgcn_mfma_f32_16x16x32_bf16(
                        af[i], bfr[j], acc[i][j], 0, 0, 0);
        }
        __syncthreads();
    }

#pragma unroll
    for (int i = 0; i < 4; ++i)
#pragma unroll
        for (int j = 0; j < 4; ++j)
#pragma unroll
            for (int r = 0; r < 4; ++r)
                C[(size_t)(m0 + wm + i * 16 + quad * 4 + r) * Nw
                  + (nc0 + wn + j * 16 + col)] = f2bf(acc[i][j][r]);
}

// ---------------------------------------------------------------------------
// Wo GEMM, SPLIT-K=2 (512 blocks, 1D grid + XCD swizzle), BK=64 + swizzle.
// z=0 -> fp32 direct to out; z=1 -> bf16 p1.
// ---------------------------------------------------------------------------
__global__ __launch_bounds__(256) void gemm_wo(const unsigned short* __restrict__ A,
                                               const unsigned short* __restrict__ Bt,
                                               float* __restrict__ Cf,
                                               unsigned short* __restrict__ Cp1) {
    __shared__ __align__(16) unsigned short As[128 * 64];
    __shared__ __align__(16) unsigned short Bs[128 * 64];

    int bid = (blockIdx.x & 7) * 64 + (blockIdx.x >> 3);   // XCD chunked swizzle
    const int z  = bid >> 8;
    const int m0 = ((bid >> 4) & 15) * 128;
    const int n0 = (bid & 15) * 128;
    const int kbase = z * 1024;

    const int tid  = threadIdx.x;
    const int w    = tid >> 6;
    const int lane = tid & 63;
    const int col  = lane & 15;
    const int quad = lane >> 4;
    const int wm = (w >> 1) * 64;
    const int wn = (w & 1) * 64;

    const int srow = lane >> 3;
    const int scol = ((lane & 7) ^ srow) * 8;
    const unsigned short* Ag = A  + (size_t)(m0 + w * 32 + srow) * HID_ + scol;
    const unsigned short* Bg = Bt + (size_t)(n0 + w * 32 + srow) * HID_ + scol;

    floatx4 acc[4][4] = {};

    for (int k0 = kbase; k0 < kbase + 1024; k0 += 64) {
#pragma unroll
        for (int c = 0; c < 4; ++c) {
            gl_lds16(Ag + (size_t)(8 * c) * HID_ + k0, &As[(w * 32 + 8 * c) * 64]);
            gl_lds16(Bg + (size_t)(8 * c) * HID_ + k0, &Bs[(w * 32 + 8 * c) * 64]);
        }
        __syncthreads();

#pragma unroll
        for (int hh = 0; hh < 2; ++hh) {
            short8 af[4], bfr[4];
#pragma unroll
            for (int i = 0; i < 4; ++i)
                af[i] = *(const short8*)&As[(wm + i * 16 + col) * 64
                                            + (((hh * 4 + quad) ^ (col & 7)) << 3)];
#pragma unroll
            for (int j = 0; j < 4; ++j)
                bfr[j] = *(const short8*)&Bs[(wn + j * 16 + col) * 64
                                             + (((hh * 4 + quad) ^ (col & 7)) << 3)];
#pragma unroll
            for (int i = 0; i < 4; ++i)
#pragma unroll
                for (int j = 0; j < 4; ++j)
                    acc[i][j] = __builtin_amdgcn_mfma_f32_16x16x32_bf16(
                        af[i], bfr[j], acc[i][j], 0, 0, 0);
        }
        __syncthreads();
    }

#pragma unroll
    for (int i = 0; i < 4; ++i)
#pragma unroll
        for (int j = 0; j < 4; ++j)
#pragma unroll
            for (int r = 0; r < 4; ++r) {
                size_t off = (size_t)(m0 + wm + i * 16 + quad * 4 + r) * HID_
                           + (n0 + wn + j * 16 + col);
                if (z == 0) Cf[off] = acc[i][j][r];
                else        Cp1[off] = f2bf(acc[i][j][r]);
            }
}

// out[i] += bf2f(p1[i]), vectorized (4 per thread). 4096 blocks x 256.
__global__ __launch_bounds__(256) void reduce_wo(float* __restrict__ out,
                                                 const unsigned short* __restrict__ p1) {
    int i4 = (blockIdx.x * 256 + threadIdx.x) * 4;
    float4 o = *(float4*)&out[i4];
    ushort4 p = *(const ushort4*)&p1[i4];
    o.x += bf2f(p.x); o.y += bf2f(p.y); o.z += bf2f(p.z); o.w += bf2f(p.w);
    *(float4*)&out[i4] = o;
}

// ---------------------------------------------------------------------------
// Fused preprocessing: bid<4096 -> X fp32->bf16; 4096..10239 -> transpose
// Wq|Wk|Wv -> WcatT; >=10240 -> transpose Wo -> WoT (grid 14336 bigws only).
// ---------------------------------------------------------------------------
__global__ __launch_bounds__(256) void prep(const float* __restrict__ X,
                                            const float* __restrict__ Wq,
                                            const float* __restrict__ Wk,
                                            const float* __restrict__ Wv,
                                            const float* __restrict__ Wo,
                                            unsigned short* __restrict__ Xbf,
                                            unsigned short* __restrict__ WcatT,
                                            unsigned short* __restrict__ WoT) {
    __shared__ float tile[32][33];
    int bid = blockIdx.x;
    if (bid < 4096) {
        int tid = bid * 256 + threadIdx.x;
        float4 v = *(const float4*)&X[(size_t)tid * 4];
        ushort4 o = {f2bf(v.x), f2bf(v.y), f2bf(v.z), f2bf(v.w)};
        *(ushort4*)&Xbf[(size_t)tid * 4] = o;
        return;
    }
    const float* W;
    unsigned short* WT;
    int N, tn0, tk0;
    if (bid < 10240) {
        bid -= 4096;
        if (bid < 4096) {
            W = Wq; WT = WcatT; N = HID_;
            tn0 = (bid & 63) * 32; tk0 = (bid >> 6) * 32;
        } else if (bid < 5120) {
            bid -= 4096;
            W = Wk; WT = WcatT + (size_t)HID_ * HID_; N = 512;
            tn0 = (bid & 15) * 32; tk0 = (bid >> 4) * 32;
        } else {
            bid -= 5120;
            W = Wv; WT = WcatT + (size_t)(HID_ + 512) * HID_; N = 512;
            tn0 = (bid & 15) * 32; tk0 = (bid >> 4) * 32;
        }
    } else {
        bid -= 10240;
        W = Wo; WT = WoT; N = HID_;
        tn0 = (bid & 63) * 32; tk0 = (bid >> 6) * 32;
    }
    const int r  = threadIdx.x >> 3;
    const int c4 = (threadIdx.x & 7) * 4;
    float4 v = *(const float4*)&W[(size_t)(tk0 + r) * N + tn0 + c4];
    tile[r][c4 + 0] = v.x;
    tile[r][c4 + 1] = v.y;
    tile[r][c4 + 2] = v.z;
    tile[r][c4 + 3] = v.w;
    __syncthreads();
    ushort4 o = {f2bf(tile[c4 + 0][r]), f2bf(tile[c4 + 1][r]),
                 f2bf(tile[c4 + 2][r]), f2bf(tile[c4 + 3][r])};
    *(ushort4*)&WT[(size_t)(tn0 + r) * HID_ + tk0 + c4] = o;
}

// Standalone Wo transpose (fallback path only).
__global__ __launch_bounds__(256) void transpose_wo(const float* __restrict__ Wo,
                                                    unsigned short* __restrict__ WoT) {
    __shared__ float tile[32][33];
    int bid = blockIdx.x;
    const int tn0 = (bid & 63) * 32;
    const int tk0 = (bid >> 6) * 32;
    const int r  = threadIdx.x >> 3;
    const int c4 = (threadIdx.x & 7) * 4;
    float4 v = *(const float4*)&Wo[(size_t)(tk0 + r) * HID_ + tn0 + c4];
    tile[r][c4 + 0] = v.x;
    tile[r][c4 + 1] = v.y;
    tile[r][c4 + 2] = v.z;
    tile[r][c4 + 3] = v.w;
    __syncthreads();
    ushort4 o = {f2bf(tile[c4 + 0][r]), f2bf(tile[c4 + 1][r]),
                 f2bf(tile[c4 + 2][r]), f2bf(tile[c4 + 3][r])};
    *(ushort4*)&WoT[(size_t)(tn0 + r) * HID_ + tk0 + c4] = o;
}

// ---------------------------------------------------------------------------
// Fused split-K reduce + RoPE + layout conversion, 4-wide vectorized.
// Q is pre-scaled by QSC (exp2-domain softmax downstream).
// ---------------------------------------------------------------------------
__global__ __launch_bounds__(256) void convert_qkv(const unsigned short* __restrict__ Qp,
                                                   const unsigned short* __restrict__ KVp,
                                                   const float* __restrict__ cosT,
                                                   const float* __restrict__ sinT,
                                                   unsigned short* __restrict__ Qbf,
                                                   unsigned short* __restrict__ Kbf,
                                                   unsigned short* __restrict__ Vt) {
    const size_t QSTR  = (size_t)2048 * 2048;   // Q partial stride (elems)
    const size_t KVSTR = (size_t)2048 * 1024;   // KV partial stride
    int tid = blockIdx.x * 256 + threadIdx.x;
    const int NQ4 = 524288;
    const int NK4 = 131072;
    if (tid < NQ4) {
        int d0 = (tid & 7) * 4;
        int h  = (tid >> 3) & 31;
        int s  = (tid >> 8) & 1023;
        int b  = tid >> 18;
        const unsigned short* row = Qp + (size_t)(b * S_ + s) * 2048 + h * HD_;
        ushort4 a0 = *(const ushort4*)&row[d0];
        ushort4 a1 = *(const ushort4*)&row[d0 + 32];
        ushort4 p0 = *(const ushort4*)&row[QSTR + d0];
        ushort4 p1 = *(const ushort4*)&row[QSTR + d0 + 32];
        float4 c0  = *(const float4*)&cosT[s * HD_ + d0];
        float4 sn0 = *(const float4*)&sinT[s * HD_ + d0];
        float4 c1  = *(const float4*)&cosT[s * HD_ + d0 + 32];
        float4 sn1 = *(const float4*)&sinT[s * HD_ + d0 + 32];
        ushort4 o0, o1;
#pragma unroll
        for (int j = 0; j < 4; ++j) {
            float x0 = bf2f(((const unsigned short*)&a0)[j]) +
                       bf2f(((const unsigned short*)&p0)[j]);
            float x1 = bf2f(((const unsigned short*)&a1)[j]) +
                       bf2f(((const unsigned short*)&p1)[j]);
            ((unsigned short*)&o0)[j] =
                f2bf((x0 * ((const float*)&c0)[j] - x1 * ((const float*)&sn0)[j]) * QSC);
            ((unsigned short*)&o1)[j] =
                f2bf((x1 * ((const float*)&c1)[j] + x0 * ((const float*)&sn1)[j]) * QSC);
        }
        unsigned short* orow = Qbf + ((size_t)(b * HQ_ + h) * S_ + s) * HD_;
        *(ushort4*)&orow[d0]      = o0;
        *(ushort4*)&orow[d0 + 32] = o1;
    } else if (tid < NQ4 + NK4) {
        tid -= NQ4;
        int d0 = (tid & 7) * 4;
        int kv = (tid >> 3) & 7;
        int s  = (tid >> 6) & 1023;
        int b  = tid >> 16;
        const unsigned short* row = KVp + (size_t)(b * S_ + s) * 1024 + kv * HD_;
        ushort4 a0 = *(const ushort4*)&row[d0];
        ushort4 a1 = *(const ushort4*)&row[d0 + 32];
        ushort4 p0 = *(const ushort4*)&row[KVSTR + d0];
        ushort4 p1 = *(const ushort4*)&row[KVSTR + d0 + 32];
        float4 c0  = *(const float4*)&cosT[s * HD_ + d0];
        float4 sn0 = *(const float4*)&sinT[s * HD_ + d0];
        float4 c1  = *(const float4*)&cosT[s * HD_ + d0 + 32];
        float4 sn1 = *(const float4*)&sinT[s * HD_ + d0 + 32];
        ushort4 o0, o1;
#pragma unroll
        for (int j = 0; j < 4; ++j) {
            float x0 = bf2f(((const unsigned short*)&a0)[j]) +
                       bf2f(((const unsigned short*)&p0)[j]);
            float x1 = bf2f(((const unsigned short*)&a1)[j]) +
                       bf2f(((const unsigned short*)&p1)[j]);
            ((unsigned short*)&o0)[j] =
                f2bf(x0 * ((const float*)&c0)[j] - x1 * ((const float*)&sn0)[j]);
            ((unsigned short*)&o1)[j] =
                f2bf(x1 * ((const float*)&c1)[j] + x0 * ((const float*)&sn1)[j]);
        }
        unsigned short* orow = Kbf + ((size_t)(b * HKV_ + kv) * S_ + s) * HD_;
        *(ushort4*)&orow[d0]      = o0;
        *(ushort4*)&orow[d0 + 32] = o1;
    } else {
        tid -= NQ4 + NK4;
        int s4 = tid & 255;
        int d  = (tid >> 8) & (HD_ - 1);
        int kv = (tid >> 14) & (HKV_ - 1);
        int b  = tid >> 17;
        int s  = s4 * 4;
        const unsigned short* base =
            KVp + ((size_t)(b * S_ + s)) * 1024 + 512 + kv * HD_ + d;
        ushort4 o;
#pragma unroll
        for (int j = 0; j < 4; ++j) {
            float v = bf2f(base[(size_t)j * 1024]) +
                      bf2f(base[KVSTR + (size_t)j * 1024]);
            ((unsigned short*)&o)[j] = f2bf(v);
        }
        *(ushort4*)&Vt[((size_t)(b * HKV_ + kv) * HD_ + d) * S_ + s] = o;
    }
}

// ---------------------------------------------------------------------------
// Flash attention: split-S, 40960 B LDS, swapped PV, defer-max (DEFER_THR in
// log2 units = r5's 8-nat semantics), exp2-domain softmax (Q pre-scaled by
// QSC in convert_qkv). Reads coalesced Qbf.
// Grid (48, 8, 2): x<32 -> split chunk (t=16+(x>>1), c=x&1); x>=32 -> t=47-x.
// ---------------------------------------------------------------------------
__global__ __launch_bounds__(256) void attn_mfma(const unsigned short* __restrict__ Qbf,
                                                 const unsigned short* __restrict__ Kbf,
                                                 const unsigned short* __restrict__ Vt,
                                                 unsigned short* __restrict__ Ctx,
                                                 float* __restrict__ PO,
                                                 float* __restrict__ ML) {
    const int x  = blockIdx.x;
    const int kv = blockIdx.y;
    const int b  = blockIdx.z;

    int tq, chunk, it0, it1;
    if (x < 32) {
        tq = 16 + (x >> 1); chunk = x & 1;
        const int ns = (32 * tq + 95) >> 6;
        const int hh = ns >> 1;
        it0 = chunk ? hh : 0;
        it1 = chunk ? ns : hh;
    } else {
        tq = 47 - x; chunk = -1;
        it0 = 0;
        it1 = (32 * tq + 95) >> 6;
    }

    const int w    = threadIdx.x >> 6;
    const int lane = threadIdx.x & 63;
    const int col  = lane & 15;
    const int quad = lane >> 4;

    const int h   = kv * 4 + w;
    const int bh  = b * HQ_ + h;
    const int bkv = b * HKV_ + kv;
    const int qw  = 32 * tq;

    __shared__ __align__(16) unsigned short sK[2][64 * 64];
    __shared__ __align__(16) unsigned short sV[2][64 * 64];
    __shared__ __align__(16) unsigned short sP[4][16 * 64];
    unsigned short* myP = sP[w];

    short8 bq[2][2];
#pragma unroll
    for (int u = 0; u < 2; ++u) {
        const unsigned short* qrow = Qbf + ((size_t)bh * S_ + qw + 16 * u + col) * HD_;
        bq[u][0] = *(const short8*)&qrow[quad * 8];
        bq[u][1] = *(const short8*)&qrow[32 + quad * 8];
    }

    const unsigned short* Kbase = Kbf + (size_t)bkv * S_ * HD_;
    const unsigned short* Vbase = Vt  + (size_t)bkv * HD_ * S_;

    const int sr  = lane >> 3;
    const int ssl = (lane & 7) ^ sr;
    const int r0  = 16 * w;

    floatx4 acc[2][4] = {};
    float m_i[2] = {-1e30f, -1e30f};
    float l_i[2] = {0.f, 0.f};

    {
        const int kb = it0 * 64;
#pragma unroll
        for (int c = 0; c < 2; ++c) {
            const int row = r0 + 8 * c + sr;
            gl_lds16(Kbase + (size_t)(kb + row) * HD_ + ssl * 8, &sK[0][(r0 + 8 * c) * 64]);
            gl_lds16(Vbase + (size_t)row * S_ + kb + ssl * 8,    &sV[0][(r0 + 8 * c) * 64]);
        }
    }
    __syncthreads();

    int cur = 0;
    for (int it = it0; it < it1; ++it) {
        const int k0 = it * 64;

        if (it + 1 < it1) {
            const int kn = k0 + 64;
#pragma unroll
            for (int c = 0; c < 2; ++c) {
                const int row = r0 + 8 * c + sr;
                gl_lds16(Kbase + (size_t)(kn + row) * HD_ + ssl * 8,
                         &sK[cur ^ 1][(r0 + 8 * c) * 64]);
                gl_lds16(Vbase + (size_t)row * S_ + kn + ssl * 8,
                         &sV[cur ^ 1][(r0 + 8 * c) * 64]);
            }
        }

        floatx4 sc[2][4];
        __builtin_amdgcn_s_setprio(1);
#pragma unroll
        for (int tt = 0; tt < 4; ++tt) {
            const int krow = 16 * tt + col;
            const unsigned short* kr = &sK[cur][krow * 64];
            short8 ak0 = *(const short8*)&kr[((quad    ) ^ (krow & 7)) * 8];
            short8 ak1 = *(const short8*)&kr[((quad + 4) ^ (krow & 7)) * 8];
#pragma unroll
            for (int u = 0; u < 2; ++u) {
                floatx4 z = {0.f, 0.f, 0.f, 0.f};
                z = __builtin_amdgcn_mfma_f32_16x16x32_bf16(ak0, bq[u][0], z, 0, 0, 0);
                z = __builtin_amdgcn_mfma_f32_16x16x32_bf16(ak1, bq[u][1], z, 0, 0, 0);
                sc[u][tt] = z;
            }
        }
        __builtin_amdgcn_s_setprio(0);

        short8 pa[2][2];
#pragma unroll
        for (int u = 0; u < 2; ++u) {
            const int qbase = qw + 16 * u;
            const int myq   = qbase + col;
            if (k0 + 63 > qbase) {
#pragma unroll
                for (int tt = 0; tt < 4; ++tt)
#pragma unroll
                    for (int r = 0; r < 4; ++r)
                        if (k0 + 16 * tt + quad * 4 + r > myq) sc[u][tt][r] = -1e30f;
            }
            float vmax = sc[u][0][0];
#pragma unroll
            for (int tt = 0; tt < 4; ++tt)
#pragma unroll
                for (int r = 0; r < 4; ++r)
                    vmax = fmaxf(vmax, sc[u][tt][r]);
            vmax = fmaxf(vmax, __shfl_xor(vmax, 16, 64));
            vmax = fmaxf(vmax, __shfl_xor(vmax, 32, 64));

            // defer-max: rescale only when some query's max grew by > DEFER_THR
            if (!__all(vmax <= m_i[u] + DEFER_THR)) {
                const float mnew  = fmaxf(m_i[u], vmax);
                const float alpha = exp2f(m_i[u] - mnew);
                m_i[u] = mnew;
                l_i[u] *= alpha;
#pragma unroll
                for (int nt = 0; nt < 4; ++nt)
#pragma unroll
                    for (int r = 0; r < 4; ++r)
                        acc[u][nt][r] *= alpha;
            }
            const float mu = m_i[u];

            float lsum = 0.f;
#pragma unroll
            for (int tt = 0; tt < 4; ++tt) {
                float p0 = exp2f(sc[u][tt][0] - mu);
                float p1 = exp2f(sc[u][tt][1] - mu);
                float p2 = exp2f(sc[u][tt][2] - mu);
                float p3 = exp2f(sc[u][tt][3] - mu);
                lsum += (p0 + p1) + (p2 + p3);
                ushort4 pk = {f2bf(p0), f2bf(p1), f2bf(p2), f2bf(p3)};
                *(ushort4*)&myP[col * 64
                                + ((((4 * tt + quad) >> 1) ^ (col & 7)) << 3)
                                + (quad & 1) * 4] = pk;
            }
            lsum += __shfl_xor(lsum, 16, 64);
            lsum += __shfl_xor(lsum, 32, 64);
            l_i[u] += lsum;

            pa[u][0] = *(const short8*)&myP[col * 64 + (((quad    ) ^ (col & 7)) << 3)];
            pa[u][1] = *(const short8*)&myP[col * 64 + (((4 + quad) ^ (col & 7)) << 3)];
        }

        __builtin_amdgcn_s_setprio(1);
#pragma unroll
        for (int nt = 0; nt < 4; ++nt) {
            const int vrow = 16 * nt + col;
            const unsigned short* vr = &sV[cur][vrow * 64];
            short8 vb0 = *(const short8*)&vr[((quad    ) ^ (vrow & 7)) * 8];
            short8 vb1 = *(const short8*)&vr[((quad + 4) ^ (vrow & 7)) * 8];
#pragma unroll
            for (int u = 0; u < 2; ++u) {
                acc[u][nt] = __builtin_amdgcn_mfma_f32_16x16x32_bf16(vb0, pa[u][0], acc[u][nt], 0, 0, 0);
                acc[u][nt] = __builtin_amdgcn_mfma_f32_16x16x32_bf16(vb1, pa[u][1], acc[u][nt], 0, 0, 0);
            }
        }
        __builtin_amdgcn_s_setprio(0);

        __syncthreads();
        cur ^= 1;
    }

    if (chunk < 0) {
#pragma unroll
        for (int u = 0; u < 2; ++u) {
            const float invl = 1.0f / l_i[u];
            unsigned short* crow =
                Ctx + (size_t)(b * S_ + qw + 16 * u + col) * HID_ + h * HD_;
#pragma unroll
            for (int nt = 0; nt < 4; ++nt) {
                ushort4 o = {f2bf(acc[u][nt][0] * invl), f2bf(acc[u][nt][1] * invl),
                             f2bf(acc[u][nt][2] * invl), f2bf(acc[u][nt][3] * invl)};
                *(ushort4*)&crow[nt * 16 + quad * 4] = o;
            }
        }
    } else {
        const int ts = tq - 16;
        const int base_row = (((b * 8 + kv) * 16 + ts) * 4 + w) * 32;
        float* POc = PO + (size_t)chunk * PCHUNK;
#pragma unroll
        for (int u = 0; u < 2; ++u) {
            float* prow = &POc[(size_t)(base_row + 16 * u + col) * 64];
#pragma unroll
            for (int nt = 0; nt < 4; ++nt)
                *(floatx4*)&prow[nt * 16 + quad * 4] = acc[u][nt];
            if (quad == 0) {
                const int rr = chunk * 32768 + base_row + 16 * u + col;
                ML[rr * 2 + 0] = m_i[u];
                ML[rr * 2 + 1] = l_i[u];
            }
        }
    }
}

// ---------------------------------------------------------------------------
// Merge the two split-S partial chunks into Ctx (rows q >= 512). m/l are in
// log2 domain -> exp2f.
// ---------------------------------------------------------------------------
__global__ __launch_bounds__(256) void merge_attn(const float* __restrict__ PO,
                                                  const float* __restrict__ ML,
                                                  unsigned short* __restrict__ Ctx) {
    const int tid = blockIdx.x * 256 + threadIdx.x;
    const int i4  = tid * 4;
    const int row = i4 >> 6;          // 0..32767
    const int d0  = i4 & 63;

    const float m0 = ML[row * 2 + 0];
    const float l0 = ML[row * 2 + 1];
    const float m1 = ML[(32768 + row) * 2 + 0];
    const float l1 = ML[(32768 + row) * 2 + 1];
    const float mf = fmaxf(m0, m1);
    const float s0 = exp2f(m0 - mf);
    const float s1 = exp2f(m1 - mf);
    const float inv = 1.0f / (l0 * s0 + l1 * s1);

    float4 o0 = *(const float4*)&PO[(size_t)row * 64 + d0];
    float4 o1 = *(const float4*)&PO[(size_t)PCHUNK + (size_t)row * 64 + d0];

    const int q  = row & 31;
    const int hh = (row >> 5) & 3;
    const int ts = (row >> 7) & 15;
    const int kv = (row >> 11) & 7;
    const int b  = row >> 14;
    const int q_abs = 512 + ts * 32 + q;
    const int h_abs = kv * 4 + hh;

    ushort4 o;
    o.x = f2bf((o0.x * s0 + o1.x * s1) * inv);
    o.y = f2bf((o0.y * s0 + o1.y * s1) * inv);
    o.z = f2bf((o0.z * s0 + o1.z * s1) * inv);
    o.w = f2bf((o0.w * s0 + o1.w * s1) * inv);
    *(ushort4*)&Ctx[((size_t)(b * S_ + q_abs)) * HID_ + h_abs * HD_ + d0] = o;
}

// ---------------------------------------------------------------------------
extern "C" void kernel_launch(void* const* d_in, const int* in_sizes, int n_in,
                              void* d_out, int out_size, void* d_ws, size_t ws_size,
                              hipStream_t stream) {
    const float* X    = (const float*)d_in[0];
    const float* cosT = (const float*)d_in[1];
    const float* sinT = (const float*)d_in[2];
    const float* Wq   = (const float*)d_in[3];
    const float* Wk   = (const float*)d_in[4];
    const float* Wv   = (const float*)d_in[5];
    const float* Wo   = (const float*)d_in[6];

    const int M = B_ * S_;          // 2048
    const size_t MB = 1024u * 1024u;

    char* ws = (char*)d_ws;
    const bool bigws = ws_size >= 64 * MB;

    if (bigws) {
        // bigws schedule (ws >= 64 MiB; observed ~256 MiB):
        //  1 prep:        Xbf ws[0,8); WcatT ws[8,20); WoT ws[48,56)
        //  2 gemm_qkv:    Qp -> d_out (2x8 MiB bf16); KVp -> ws[20,28)
        //  3 convert_qkv: Qbf ws[0,8) (overwrites Xbf after gemm), Kbf ws[8,10),
        //                 Vt ws[10,12)
        //  4 attn:        Ctx -> ws[20,28); PO -> d_out (Qp dead); ML -> ws[45,45.5)
        //  5 merge_attn
        //  6 gemm_wo:     z=0 fp32 -> d_out; z=1 bf16 -> ws[0,8) (Qbf dead)
        //  7 reduce_wo
        unsigned short* Xbf   = (unsigned short*)(ws);
        unsigned short* Qbf   = (unsigned short*)(ws);
        unsigned short* WcatT = (unsigned short*)(ws + 8 * MB);
        unsigned short* Kbf   = (unsigned short*)(ws + 8 * MB);
        unsigned short* Vt    = (unsigned short*)(ws + 10 * MB);
        unsigned short* KVp   = (unsigned short*)(ws + 20 * MB);
        unsigned short* Ctxbf = (unsigned short*)(ws + 20 * MB);
        float*          MLb   = (float*)(ws + 45 * MB);
        unsigned short* WoT   = (unsigned short*)(ws + 48 * MB);
        unsigned short* Wop1  = (unsigned short*)(ws);
        unsigned short* Qp    = (unsigned short*)d_out;
        float*          PO    = (float*)d_out;
        float* out = (float*)d_out;

        prep<<<14336, 256, 0, stream>>>(X, Wq, Wk, Wv, Wo, Xbf, WcatT, WoT);
        gemm_qkv<<<768, 256, 0, stream>>>(Xbf, WcatT, Qp, KVp);
        convert_qkv<<<3584, 256, 0, stream>>>(Qp, KVp, cosT, sinT, Qbf, Kbf, Vt);
        attn_mfma<<<dim3(48, HKV_, B_), 256, 0, stream>>>(Qbf, Kbf, Vt,
                                                          Ctxbf, PO, MLb);
        merge_attn<<<2048, 256, 0, stream>>>(PO, MLb, Ctxbf);
        gemm_wo<<<512, 256, 0, stream>>>(Ctxbf, WoT, out, Wop1);
        reduce_wo<<<(M * HID_ / 4) / 256, 256, 0, stream>>>(out, Wop1);
    } else {
        // fallback schedule (ws >= 28 MiB): WoT transposed after merge.
        unsigned short* Xbf   = (unsigned short*)(ws);
        unsigned short* Qbf   = (unsigned short*)(ws);
        unsigned short* WcatT = (unsigned short*)(ws + 8 * MB);
        unsigned short* Kbf   = (unsigned short*)(ws + 8 * MB);
        unsigned short* Vt    = (unsigned short*)(ws + 10 * MB);
        unsigned short* WoT   = (unsigned short*)(ws + 12 * MB);
        float*          MLb   = (float*)(ws + 12 * MB);
        unsigned short* KVp   = (unsigned short*)(ws + 20 * MB);
        unsigned short* Ctxbf = (unsigned short*)(ws + 20 * MB);
        unsigned short* Wop1  = (unsigned short*)(ws);
        unsigned short* Qp    = (unsigned short*)d_out;
        float*          PO    = (float*)d_out;
        float* out = (float*)d_out;

        prep<<<10240, 256, 0, stream>>>(X, Wq, Wk, Wv, Wo, Xbf, WcatT, WoT);
        gemm_qkv<<<768, 256, 0, stream>>>(Xbf, WcatT, Qp, KVp);
        convert_qkv<<<3584, 256, 0, stream>>>(Qp, KVp, cosT, sinT, Qbf, Kbf, Vt);
        attn_mfma<<<dim3(48, HKV_, B_), 256, 0, stream>>>(Qbf, Kbf, Vt,
                                                          Ctxbf, PO, MLb);
        merge_attn<<<2048, 256, 0, stream>>>(PO, MLb, Ctxbf);
        transpose_wo<<<4096, 256, 0, stream>>>(Wo, WoT);
        gemm_wo<<<512, 256, 0, stream>>>(Ctxbf, WoT, out, Wop1);
        reduce_wo<<<(M * HID_ / 4) / 256, 256, 0, stream>>>(out, Wop1);
    }
}

// Round 9
// 224.299 us; speedup vs baseline: 1.0220x; 1.0220x over previous
//
#include <hip/hip_runtime.h>
#include <math.h>

#define B_   2
#define S_   1024
#define HID_ 2048
#define HQ_  32
#define HKV_ 8
#define HD_  64
#define NQKV 3072   // HID + 2*HKV*HD

#define PCHUNK 2097152   // split-attn partial-O chunk stride (fp32 elems)
#define QSC   (0.125f * 1.44269504089f)   // RoPE-Q scale incl. log2(e) for exp2-domain softmax
#define DEFER_THR 11.54f                  // defer-max threshold in log2 units (= 8 nats)

using short8  = __attribute__((ext_vector_type(8))) short;
using floatx4 = __attribute__((ext_vector_type(4))) float;

__device__ __forceinline__ unsigned short f2bf(float x) {
    unsigned int u = __builtin_bit_cast(unsigned int, x);
    u += 0x7FFFu + ((u >> 16) & 1u);
    return (unsigned short)(u >> 16);
}
__device__ __forceinline__ float bf2f(unsigned short u) {
    return __builtin_bit_cast(float, (unsigned int)u << 16);
}
// Raw v_exp_f32 (hardware 2^x, 1 instruction) — library exp2f is OCML's
// precise path (~5 VALU ops: denormal handling); that cost was the r7/r8
// attn regression (VALUBusy 29->35).
__device__ __forceinline__ float fexp2(float x) {
    return __builtin_amdgcn_exp2f(x);
}

__device__ __forceinline__ void gl_lds16(const unsigned short* g, unsigned short* l) {
    __builtin_amdgcn_global_load_lds(
        (const __attribute__((address_space(1))) void*)g,
        (__attribute__((address_space(3))) void*)l, 16, 0, 0);
}

// ---------------------------------------------------------------------------
// QKV GEMM, SPLIT-K=2 (768 blocks = 3/CU). 128x128 tile, BK=64, XOR-swizzled
// LDS. XCD-aware block swizzle: 768%8==0 -> bijective chunked remap.
// ---------------------------------------------------------------------------
__global__ __launch_bounds__(256) void gemm_qkv(const unsigned short* __restrict__ A,
                                                const unsigned short* __restrict__ Bt,
                                                unsigned short* __restrict__ Qp,
                                                unsigned short* __restrict__ KVp) {
    __shared__ __align__(16) unsigned short As[128 * 64];
    __shared__ __align__(16) unsigned short Bs[128 * 64];

    int bid = (blockIdx.x & 7) * 96 + (blockIdx.x >> 3);   // XCD chunked swizzle
    int m0, n0, z, Nw, nc0;
    unsigned short* C;
    if (bid < 512) {
        n0 = (bid & 15) * 128; m0 = ((bid >> 4) & 15) * 128; z = bid >> 8;
        C = Qp + (size_t)z * 2048 * 2048; Nw = 2048; nc0 = n0;
    } else {
        bid -= 512;
        n0 = 2048 + (bid & 7) * 128; m0 = ((bid >> 3) & 15) * 128; z = bid >> 7;
        C = KVp + (size_t)z * 2048 * 1024; Nw = 1024; nc0 = n0 - 2048;
    }
    const int kbase = z * 1024;

    const int tid  = threadIdx.x;
    const int w    = tid >> 6;
    const int lane = tid & 63;
    const int col  = lane & 15;
    const int quad = lane >> 4;
    const int wm = (w >> 1) * 64;
    const int wn = (w & 1) * 64;

    const int srow = lane >> 3;
    const int scol = ((lane & 7) ^ srow) * 8;
    const unsigned short* Ag = A  + (size_t)(m0 + w * 32 + srow) * HID_ + scol;
    const unsigned short* Bg = Bt + (size_t)(n0 + w * 32 + srow) * HID_ + scol;

    floatx4 acc[4][4] = {};

    for (int k0 = kbase; k0 < kbase + 1024; k0 += 64) {
#pragma unroll
        for (int c = 0; c < 4; ++c) {
            gl_lds16(Ag + (size_t)(8 * c) * HID_ + k0, &As[(w * 32 + 8 * c) * 64]);
            gl_lds16(Bg + (size_t)(8 * c) * HID_ + k0, &Bs[(w * 32 + 8 * c) * 64]);
        }
        __syncthreads();

#pragma unroll
        for (int hh = 0; hh < 2; ++hh) {
            short8 af[4], bfr[4];
#pragma unroll
            for (int i = 0; i < 4; ++i)
                af[i] = *(const short8*)&As[(wm + i * 16 + col) * 64
                                            + (((hh * 4 + quad) ^ (col & 7)) << 3)];
#pragma unroll
            for (int j = 0; j < 4; ++j)
                bfr[j] = *(const short8*)&Bs[(wn + j * 16 + col) * 64
                                             + (((hh * 4 + quad) ^ (col & 7)) << 3)];
#pragma unroll
            for (int i = 0; i < 4; ++i)
#pragma unroll
                for (int j = 0; j < 4; ++j)
                    acc[i][j] = __builtin_amdgcn_mfma_f32_16x16x32_bf16(
                        af[i], bfr[j], acc[i][j], 0, 0, 0);
        }
        __syncthreads();
    }

#pragma unroll
    for (int i = 0; i < 4; ++i)
#pragma unroll
        for (int j = 0; j < 4; ++j)
#pragma unroll
            for (int r = 0; r < 4; ++r)
                C[(size_t)(m0 + wm + i * 16 + quad * 4 + r) * Nw
                  + (nc0 + wn + j * 16 + col)] = f2bf(acc[i][j][r]);
}

// ---------------------------------------------------------------------------
// Wo GEMM, SPLIT-K=2 (512 blocks, 1D grid + XCD swizzle), BK=64 + swizzle.
// z=0 -> fp32 direct to out; z=1 -> bf16 p1.
// ---------------------------------------------------------------------------
__global__ __launch_bounds__(256) void gemm_wo(const unsigned short* __restrict__ A,
                                               const unsigned short* __restrict__ Bt,
                                               float* __restrict__ Cf,
                                               unsigned short* __restrict__ Cp1) {
    __shared__ __align__(16) unsigned short As[128 * 64];
    __shared__ __align__(16) unsigned short Bs[128 * 64];

    int bid = (blockIdx.x & 7) * 64 + (blockIdx.x >> 3);   // XCD chunked swizzle
    const int z  = bid >> 8;
    const int m0 = ((bid >> 4) & 15) * 128;
    const int n0 = (bid & 15) * 128;
    const int kbase = z * 1024;

    const int tid  = threadIdx.x;
    const int w    = tid >> 6;
    const int lane = tid & 63;
    const int col  = lane & 15;
    const int quad = lane >> 4;
    const int wm = (w >> 1) * 64;
    const int wn = (w & 1) * 64;

    const int srow = lane >> 3;
    const int scol = ((lane & 7) ^ srow) * 8;
    const unsigned short* Ag = A  + (size_t)(m0 + w * 32 + srow) * HID_ + scol;
    const unsigned short* Bg = Bt + (size_t)(n0 + w * 32 + srow) * HID_ + scol;

    floatx4 acc[4][4] = {};

    for (int k0 = kbase; k0 < kbase + 1024; k0 += 64) {
#pragma unroll
        for (int c = 0; c < 4; ++c) {
            gl_lds16(Ag + (size_t)(8 * c) * HID_ + k0, &As[(w * 32 + 8 * c) * 64]);
            gl_lds16(Bg + (size_t)(8 * c) * HID_ + k0, &Bs[(w * 32 + 8 * c) * 64]);
        }
        __syncthreads();

#pragma unroll
        for (int hh = 0; hh < 2; ++hh) {
            short8 af[4], bfr[4];
#pragma unroll
            for (int i = 0; i < 4; ++i)
                af[i] = *(const short8*)&As[(wm + i * 16 + col) * 64
                                            + (((hh * 4 + quad) ^ (col & 7)) << 3)];
#pragma unroll
            for (int j = 0; j < 4; ++j)
                bfr[j] = *(const short8*)&Bs[(wn + j * 16 + col) * 64
                                             + (((hh * 4 + quad) ^ (col & 7)) << 3)];
#pragma unroll
            for (int i = 0; i < 4; ++i)
#pragma unroll
                for (int j = 0; j < 4; ++j)
                    acc[i][j] = __builtin_amdgcn_mfma_f32_16x16x32_bf16(
                        af[i], bfr[j], acc[i][j], 0, 0, 0);
        }
        __syncthreads();
    }

#pragma unroll
    for (int i = 0; i < 4; ++i)
#pragma unroll
        for (int j = 0; j < 4; ++j)
#pragma unroll
            for (int r = 0; r < 4; ++r) {
                size_t off = (size_t)(m0 + wm + i * 16 + quad * 4 + r) * HID_
                           + (n0 + wn + j * 16 + col);
                if (z == 0) Cf[off] = acc[i][j][r];
                else        Cp1[off] = f2bf(acc[i][j][r]);
            }
}

// out[i] += bf2f(p1[i]), vectorized (4 per thread). 4096 blocks x 256.
__global__ __launch_bounds__(256) void reduce_wo(float* __restrict__ out,
                                                 const unsigned short* __restrict__ p1) {
    int i4 = (blockIdx.x * 256 + threadIdx.x) * 4;
    float4 o = *(float4*)&out[i4];
    ushort4 p = *(const ushort4*)&p1[i4];
    o.x += bf2f(p.x); o.y += bf2f(p.y); o.z += bf2f(p.z); o.w += bf2f(p.w);
    *(float4*)&out[i4] = o;
}

// ---------------------------------------------------------------------------
// Fused preprocessing: bid<4096 -> X fp32->bf16; 4096..10239 -> transpose
// Wq|Wk|Wv -> WcatT; >=10240 -> transpose Wo -> WoT (grid 14336 bigws only).
// ---------------------------------------------------------------------------
__global__ __launch_bounds__(256) void prep(const float* __restrict__ X,
                                            const float* __restrict__ Wq,
                                            const float* __restrict__ Wk,
                                            const float* __restrict__ Wv,
                                            const float* __restrict__ Wo,
                                            unsigned short* __restrict__ Xbf,
                                            unsigned short* __restrict__ WcatT,
                                            unsigned short* __restrict__ WoT) {
    __shared__ float tile[32][33];
    int bid = blockIdx.x;
    if (bid < 4096) {
        int tid = bid * 256 + threadIdx.x;
        float4 v = *(const float4*)&X[(size_t)tid * 4];
        ushort4 o = {f2bf(v.x), f2bf(v.y), f2bf(v.z), f2bf(v.w)};
        *(ushort4*)&Xbf[(size_t)tid * 4] = o;
        return;
    }
    const float* W;
    unsigned short* WT;
    int N, tn0, tk0;
    if (bid < 10240) {
        bid -= 4096;
        if (bid < 4096) {
            W = Wq; WT = WcatT; N = HID_;
            tn0 = (bid & 63) * 32; tk0 = (bid >> 6) * 32;
        } else if (bid < 5120) {
            bid -= 4096;
            W = Wk; WT = WcatT + (size_t)HID_ * HID_; N = 512;
            tn0 = (bid & 15) * 32; tk0 = (bid >> 4) * 32;
        } else {
            bid -= 5120;
            W = Wv; WT = WcatT + (size_t)(HID_ + 512) * HID_; N = 512;
            tn0 = (bid & 15) * 32; tk0 = (bid >> 4) * 32;
        }
    } else {
        bid -= 10240;
        W = Wo; WT = WoT; N = HID_;
        tn0 = (bid & 63) * 32; tk0 = (bid >> 6) * 32;
    }
    const int r  = threadIdx.x >> 3;
    const int c4 = (threadIdx.x & 7) * 4;
    float4 v = *(const float4*)&W[(size_t)(tk0 + r) * N + tn0 + c4];
    tile[r][c4 + 0] = v.x;
    tile[r][c4 + 1] = v.y;
    tile[r][c4 + 2] = v.z;
    tile[r][c4 + 3] = v.w;
    __syncthreads();
    ushort4 o = {f2bf(tile[c4 + 0][r]), f2bf(tile[c4 + 1][r]),
                 f2bf(tile[c4 + 2][r]), f2bf(tile[c4 + 3][r])};
    *(ushort4*)&WT[(size_t)(tn0 + r) * HID_ + tk0 + c4] = o;
}

// Standalone Wo transpose (fallback path only).
__global__ __launch_bounds__(256) void transpose_wo(const float* __restrict__ Wo,
                                                    unsigned short* __restrict__ WoT) {
    __shared__ float tile[32][33];
    int bid = blockIdx.x;
    const int tn0 = (bid & 63) * 32;
    const int tk0 = (bid >> 6) * 32;
    const int r  = threadIdx.x >> 3;
    const int c4 = (threadIdx.x & 7) * 4;
    float4 v = *(const float4*)&Wo[(size_t)(tk0 + r) * HID_ + tn0 + c4];
    tile[r][c4 + 0] = v.x;
    tile[r][c4 + 1] = v.y;
    tile[r][c4 + 2] = v.z;
    tile[r][c4 + 3] = v.w;
    __syncthreads();
    ushort4 o = {f2bf(tile[c4 + 0][r]), f2bf(tile[c4 + 1][r]),
                 f2bf(tile[c4 + 2][r]), f2bf(tile[c4 + 3][r])};
    *(ushort4*)&WoT[(size_t)(tn0 + r) * HID_ + tk0 + c4] = o;
}

// ---------------------------------------------------------------------------
// Fused split-K reduce + RoPE + layout conversion, 4-wide vectorized.
// Q is pre-scaled by QSC (exp2-domain softmax downstream).
// ---------------------------------------------------------------------------
__global__ __launch_bounds__(256) void convert_qkv(const unsigned short* __restrict__ Qp,
                                                   const unsigned short* __restrict__ KVp,
                                                   const float* __restrict__ cosT,
                                                   const float* __restrict__ sinT,
                                                   unsigned short* __restrict__ Qbf,
                                                   unsigned short* __restrict__ Kbf,
                                                   unsigned short* __restrict__ Vt) {
    const size_t QSTR  = (size_t)2048 * 2048;   // Q partial stride (elems)
    const size_t KVSTR = (size_t)2048 * 1024;   // KV partial stride
    int tid = blockIdx.x * 256 + threadIdx.x;
    const int NQ4 = 524288;
    const int NK4 = 131072;
    if (tid < NQ4) {
        int d0 = (tid & 7) * 4;
        int h  = (tid >> 3) & 31;
        int s  = (tid >> 8) & 1023;
        int b  = tid >> 18;
        const unsigned short* row = Qp + (size_t)(b * S_ + s) * 2048 + h * HD_;
        ushort4 a0 = *(const ushort4*)&row[d0];
        ushort4 a1 = *(const ushort4*)&row[d0 + 32];
        ushort4 p0 = *(const ushort4*)&row[QSTR + d0];
        ushort4 p1 = *(const ushort4*)&row[QSTR + d0 + 32];
        float4 c0  = *(const float4*)&cosT[s * HD_ + d0];
        float4 sn0 = *(const float4*)&sinT[s * HD_ + d0];
        float4 c1  = *(const float4*)&cosT[s * HD_ + d0 + 32];
        float4 sn1 = *(const float4*)&sinT[s * HD_ + d0 + 32];
        ushort4 o0, o1;
#pragma unroll
        for (int j = 0; j < 4; ++j) {
            float x0 = bf2f(((const unsigned short*)&a0)[j]) +
                       bf2f(((const unsigned short*)&p0)[j]);
            float x1 = bf2f(((const unsigned short*)&a1)[j]) +
                       bf2f(((const unsigned short*)&p1)[j]);
            ((unsigned short*)&o0)[j] =
                f2bf((x0 * ((const float*)&c0)[j] - x1 * ((const float*)&sn0)[j]) * QSC);
            ((unsigned short*)&o1)[j] =
                f2bf((x1 * ((const float*)&c1)[j] + x0 * ((const float*)&sn1)[j]) * QSC);
        }
        unsigned short* orow = Qbf + ((size_t)(b * HQ_ + h) * S_ + s) * HD_;
        *(ushort4*)&orow[d0]      = o0;
        *(ushort4*)&orow[d0 + 32] = o1;
    } else if (tid < NQ4 + NK4) {
        tid -= NQ4;
        int d0 = (tid & 7) * 4;
        int kv = (tid >> 3) & 7;
        int s  = (tid >> 6) & 1023;
        int b  = tid >> 16;
        const unsigned short* row = KVp + (size_t)(b * S_ + s) * 1024 + kv * HD_;
        ushort4 a0 = *(const ushort4*)&row[d0];
        ushort4 a1 = *(const ushort4*)&row[d0 + 32];
        ushort4 p0 = *(const ushort4*)&row[KVSTR + d0];
        ushort4 p1 = *(const ushort4*)&row[KVSTR + d0 + 32];
        float4 c0  = *(const float4*)&cosT[s * HD_ + d0];
        float4 sn0 = *(const float4*)&sinT[s * HD_ + d0];
        float4 c1  = *(const float4*)&cosT[s * HD_ + d0 + 32];
        float4 sn1 = *(const float4*)&sinT[s * HD_ + d0 + 32];
        ushort4 o0, o1;
#pragma unroll
        for (int j = 0; j < 4; ++j) {
            float x0 = bf2f(((const unsigned short*)&a0)[j]) +
                       bf2f(((const unsigned short*)&p0)[j]);
            float x1 = bf2f(((const unsigned short*)&a1)[j]) +
                       bf2f(((const unsigned short*)&p1)[j]);
            ((unsigned short*)&o0)[j] =
                f2bf(x0 * ((const float*)&c0)[j] - x1 * ((const float*)&sn0)[j]);
            ((unsigned short*)&o1)[j] =
                f2bf(x1 * ((const float*)&c1)[j] + x0 * ((const float*)&sn1)[j]);
        }
        unsigned short* orow = Kbf + ((size_t)(b * HKV_ + kv) * S_ + s) * HD_;
        *(ushort4*)&orow[d0]      = o0;
        *(ushort4*)&orow[d0 + 32] = o1;
    } else {
        tid -= NQ4 + NK4;
        int s4 = tid & 255;
        int d  = (tid >> 8) & (HD_ - 1);
        int kv = (tid >> 14) & (HKV_ - 1);
        int b  = tid >> 17;
        int s  = s4 * 4;
        const unsigned short* base =
            KVp + ((size_t)(b * S_ + s)) * 1024 + 512 + kv * HD_ + d;
        ushort4 o;
#pragma unroll
        for (int j = 0; j < 4; ++j) {
            float v = bf2f(base[(size_t)j * 1024]) +
                      bf2f(base[KVSTR + (size_t)j * 1024]);
            ((unsigned short*)&o)[j] = f2bf(v);
        }
        *(ushort4*)&Vt[((size_t)(b * HKV_ + kv) * HD_ + d) * S_ + s] = o;
    }
}

// ---------------------------------------------------------------------------
// Flash attention: split-S, 40960 B LDS, swapped PV, defer-max, exp2-domain
// softmax via raw v_exp_f32 (fexp2). Reads coalesced Qbf.
// Grid (48, 8, 2): x<32 -> split chunk (t=16+(x>>1), c=x&1); x>=32 -> t=47-x.
// ---------------------------------------------------------------------------
__global__ __launch_bounds__(256) void attn_mfma(const unsigned short* __restrict__ Qbf,
                                                 const unsigned short* __restrict__ Kbf,
                                                 const unsigned short* __restrict__ Vt,
                                                 unsigned short* __restrict__ Ctx,
                                                 float* __restrict__ PO,
                                                 float* __restrict__ ML) {
    const int x  = blockIdx.x;
    const int kv = blockIdx.y;
    const int b  = blockIdx.z;

    int tq, chunk, it0, it1;
    if (x < 32) {
        tq = 16 + (x >> 1); chunk = x & 1;
        const int ns = (32 * tq + 95) >> 6;
        const int hh = ns >> 1;
        it0 = chunk ? hh : 0;
        it1 = chunk ? ns : hh;
    } else {
        tq = 47 - x; chunk = -1;
        it0 = 0;
        it1 = (32 * tq + 95) >> 6;
    }

    const int w    = threadIdx.x >> 6;
    const int lane = threadIdx.x & 63;
    const int col  = lane & 15;
    const int quad = lane >> 4;

    const int h   = kv * 4 + w;
    const int bh  = b * HQ_ + h;
    const int bkv = b * HKV_ + kv;
    const int qw  = 32 * tq;

    __shared__ __align__(16) unsigned short sK[2][64 * 64];
    __shared__ __align__(16) unsigned short sV[2][64 * 64];
    __shared__ __align__(16) unsigned short sP[4][16 * 64];
    unsigned short* myP = sP[w];

    short8 bq[2][2];
#pragma unroll
    for (int u = 0; u < 2; ++u) {
        const unsigned short* qrow = Qbf + ((size_t)bh * S_ + qw + 16 * u + col) * HD_;
        bq[u][0] = *(const short8*)&qrow[quad * 8];
        bq[u][1] = *(const short8*)&qrow[32 + quad * 8];
    }

    const unsigned short* Kbase = Kbf + (size_t)bkv * S_ * HD_;
    const unsigned short* Vbase = Vt  + (size_t)bkv * HD_ * S_;

    const int sr  = lane >> 3;
    const int ssl = (lane & 7) ^ sr;
    const int r0  = 16 * w;

    floatx4 acc[2][4] = {};
    float m_i[2] = {-1e30f, -1e30f};
    float l_i[2] = {0.f, 0.f};

    {
        const int kb = it0 * 64;
#pragma unroll
        for (int c = 0; c < 2; ++c) {
            const int row = r0 + 8 * c + sr;
            gl_lds16(Kbase + (size_t)(kb + row) * HD_ + ssl * 8, &sK[0][(r0 + 8 * c) * 64]);
            gl_lds16(Vbase + (size_t)row * S_ + kb + ssl * 8,    &sV[0][(r0 + 8 * c) * 64]);
        }
    }
    __syncthreads();

    int cur = 0;
    for (int it = it0; it < it1; ++it) {
        const int k0 = it * 64;

        if (it + 1 < it1) {
            const int kn = k0 + 64;
#pragma unroll
            for (int c = 0; c < 2; ++c) {
                const int row = r0 + 8 * c + sr;
                gl_lds16(Kbase + (size_t)(kn + row) * HD_ + ssl * 8,
                         &sK[cur ^ 1][(r0 + 8 * c) * 64]);
                gl_lds16(Vbase + (size_t)row * S_ + kn + ssl * 8,
                         &sV[cur ^ 1][(r0 + 8 * c) * 64]);
            }
        }

        floatx4 sc[2][4];
        __builtin_amdgcn_s_setprio(1);
#pragma unroll
        for (int tt = 0; tt < 4; ++tt) {
            const int krow = 16 * tt + col;
            const unsigned short* kr = &sK[cur][krow * 64];
            short8 ak0 = *(const short8*)&kr[((quad    ) ^ (krow & 7)) * 8];
            short8 ak1 = *(const short8*)&kr[((quad + 4) ^ (krow & 7)) * 8];
#pragma unroll
            for (int u = 0; u < 2; ++u) {
                floatx4 z = {0.f, 0.f, 0.f, 0.f};
                z = __builtin_amdgcn_mfma_f32_16x16x32_bf16(ak0, bq[u][0], z, 0, 0, 0);
                z = __builtin_amdgcn_mfma_f32_16x16x32_bf16(ak1, bq[u][1], z, 0, 0, 0);
                sc[u][tt] = z;
            }
        }
        __builtin_amdgcn_s_setprio(0);

        short8 pa[2][2];
#pragma unroll
        for (int u = 0; u < 2; ++u) {
            const int qbase = qw + 16 * u;
            const int myq   = qbase + col;
            if (k0 + 63 > qbase) {
#pragma unroll
                for (int tt = 0; tt < 4; ++tt)
#pragma unroll
                    for (int r = 0; r < 4; ++r)
                        if (k0 + 16 * tt + quad * 4 + r > myq) sc[u][tt][r] = -1e30f;
            }
            float vmax = sc[u][0][0];
#pragma unroll
            for (int tt = 0; tt < 4; ++tt)
#pragma unroll
                for (int r = 0; r < 4; ++r)
                    vmax = fmaxf(vmax, sc[u][tt][r]);
            vmax = fmaxf(vmax, __shfl_xor(vmax, 16, 64));
            vmax = fmaxf(vmax, __shfl_xor(vmax, 32, 64));

            // defer-max: rescale only when some query's max grew by > DEFER_THR
            if (!__all(vmax <= m_i[u] + DEFER_THR)) {
                const float mnew  = fmaxf(m_i[u], vmax);
                const float alpha = fexp2(m_i[u] - mnew);
                m_i[u] = mnew;
                l_i[u] *= alpha;
#pragma unroll
                for (int nt = 0; nt < 4; ++nt)
#pragma unroll
                    for (int r = 0; r < 4; ++r)
                        acc[u][nt][r] *= alpha;
            }
            const float mu = m_i[u];

            float lsum = 0.f;
#pragma unroll
            for (int tt = 0; tt < 4; ++tt) {
                float p0 = fexp2(sc[u][tt][0] - mu);
                float p1 = fexp2(sc[u][tt][1] - mu);
                float p2 = fexp2(sc[u][tt][2] - mu);
                float p3 = fexp2(sc[u][tt][3] - mu);
                lsum += (p0 + p1) + (p2 + p3);
                ushort4 pk = {f2bf(p0), f2bf(p1), f2bf(p2), f2bf(p3)};
                *(ushort4*)&myP[col * 64
                                + ((((4 * tt + quad) >> 1) ^ (col & 7)) << 3)
                                + (quad & 1) * 4] = pk;
            }
            lsum += __shfl_xor(lsum, 16, 64);
            lsum += __shfl_xor(lsum, 32, 64);
            l_i[u] += lsum;

            pa[u][0] = *(const short8*)&myP[col * 64 + (((quad    ) ^ (col & 7)) << 3)];
            pa[u][1] = *(const short8*)&myP[col * 64 + (((4 + quad) ^ (col & 7)) << 3)];
        }

        __builtin_amdgcn_s_setprio(1);
#pragma unroll
        for (int nt = 0; nt < 4; ++nt) {
            const int vrow = 16 * nt + col;
            const unsigned short* vr = &sV[cur][vrow * 64];
            short8 vb0 = *(const short8*)&vr[((quad    ) ^ (vrow & 7)) * 8];
            short8 vb1 = *(const short8*)&vr[((quad + 4) ^ (vrow & 7)) * 8];
#pragma unroll
            for (int u = 0; u < 2; ++u) {
                acc[u][nt] = __builtin_amdgcn_mfma_f32_16x16x32_bf16(vb0, pa[u][0], acc[u][nt], 0, 0, 0);
                acc[u][nt] = __builtin_amdgcn_mfma_f32_16x16x32_bf16(vb1, pa[u][1], acc[u][nt], 0, 0, 0);
            }
        }
        __builtin_amdgcn_s_setprio(0);

        __syncthreads();
        cur ^= 1;
    }

    if (chunk < 0) {
#pragma unroll
        for (int u = 0; u < 2; ++u) {
            const float invl = 1.0f / l_i[u];
            unsigned short* crow =
                Ctx + (size_t)(b * S_ + qw + 16 * u + col) * HID_ + h * HD_;
#pragma unroll
            for (int nt = 0; nt < 4; ++nt) {
                ushort4 o = {f2bf(acc[u][nt][0] * invl), f2bf(acc[u][nt][1] * invl),
                             f2bf(acc[u][nt][2] * invl), f2bf(acc[u][nt][3] * invl)};
                *(ushort4*)&crow[nt * 16 + quad * 4] = o;
            }
        }
    } else {
        const int ts = tq - 16;
        const int base_row = (((b * 8 + kv) * 16 + ts) * 4 + w) * 32;
        float* POc = PO + (size_t)chunk * PCHUNK;
#pragma unroll
        for (int u = 0; u < 2; ++u) {
            float* prow = &POc[(size_t)(base_row + 16 * u + col) * 64];
#pragma unroll
            for (int nt = 0; nt < 4; ++nt)
                *(floatx4*)&prow[nt * 16 + quad * 4] = acc[u][nt];
            if (quad == 0) {
                const int rr = chunk * 32768 + base_row + 16 * u + col;
                ML[rr * 2 + 0] = m_i[u];
                ML[rr * 2 + 1] = l_i[u];
            }
        }
    }
}

// ---------------------------------------------------------------------------
// Merge the two split-S partial chunks into Ctx (rows q >= 512). m/l are in
// log2 domain -> fexp2.
// ---------------------------------------------------------------------------
__global__ __launch_bounds__(256) void merge_attn(const float* __restrict__ PO,
                                                  const float* __restrict__ ML,
                                                  unsigned short* __restrict__ Ctx) {
    const int tid = blockIdx.x * 256 + threadIdx.x;
    const int i4  = tid * 4;
    const int row = i4 >> 6;          // 0..32767
    const int d0  = i4 & 63;

    const float m0 = ML[row * 2 + 0];
    const float l0 = ML[row * 2 + 1];
    const float m1 = ML[(32768 + row) * 2 + 0];
    const float l1 = ML[(32768 + row) * 2 + 1];
    const float mf = fmaxf(m0, m1);
    const float s0 = fexp2(m0 - mf);
    const float s1 = fexp2(m1 - mf);
    const float inv = 1.0f / (l0 * s0 + l1 * s1);

    float4 o0 = *(const float4*)&PO[(size_t)row * 64 + d0];
    float4 o1 = *(const float4*)&PO[(size_t)PCHUNK + (size_t)row * 64 + d0];

    const int q  = row & 31;
    const int hh = (row >> 5) & 3;
    const int ts = (row >> 7) & 15;
    const int kv = (row >> 11) & 7;
    const int b  = row >> 14;
    const int q_abs = 512 + ts * 32 + q;
    const int h_abs = kv * 4 + hh;

    ushort4 o;
    o.x = f2bf((o0.x * s0 + o1.x * s1) * inv);
    o.y = f2bf((o0.y * s0 + o1.y * s1) * inv);
    o.z = f2bf((o0.z * s0 + o1.z * s1) * inv);
    o.w = f2bf((o0.w * s0 + o1.w * s1) * inv);
    *(ushort4*)&Ctx[((size_t)(b * S_ + q_abs)) * HID_ + h_abs * HD_ + d0] = o;
}

// ---------------------------------------------------------------------------
extern "C" void kernel_launch(void* const* d_in, const int* in_sizes, int n_in,
                              void* d_out, int out_size, void* d_ws, size_t ws_size,
                              hipStream_t stream) {
    const float* X    = (const float*)d_in[0];
    const float* cosT = (const float*)d_in[1];
    const float* sinT = (const float*)d_in[2];
    const float* Wq   = (const float*)d_in[3];
    const float* Wk   = (const float*)d_in[4];
    const float* Wv   = (const float*)d_in[5];
    const float* Wo   = (const float*)d_in[6];

    const int M = B_ * S_;          // 2048
    const size_t MB = 1024u * 1024u;

    char* ws = (char*)d_ws;
    const bool bigws = ws_size >= 64 * MB;

    if (bigws) {
        // bigws schedule (ws >= 64 MiB; observed ~256 MiB):
        //  1 prep:        Xbf ws[0,8); WcatT ws[8,20); WoT ws[48,56)
        //  2 gemm_qkv:    Qp -> d_out (2x8 MiB bf16); KVp -> ws[20,28)
        //  3 convert_qkv: Qbf ws[0,8) (overwrites Xbf after gemm), Kbf ws[8,10),
        //                 Vt ws[10,12)
        //  4 attn:        Ctx -> ws[20,28); PO -> d_out (Qp dead); ML -> ws[45,45.5)
        //  5 merge_attn
        //  6 gemm_wo:     z=0 fp32 -> d_out; z=1 bf16 -> ws[0,8) (Qbf dead)
        //  7 reduce_wo
        unsigned short* Xbf   = (unsigned short*)(ws);
        unsigned short* Qbf   = (unsigned short*)(ws);
        unsigned short* WcatT = (unsigned short*)(ws + 8 * MB);
        unsigned short* Kbf   = (unsigned short*)(ws + 8 * MB);
        unsigned short* Vt    = (unsigned short*)(ws + 10 * MB);
        unsigned short* KVp   = (unsigned short*)(ws + 20 * MB);
        unsigned short* Ctxbf = (unsigned short*)(ws + 20 * MB);
        float*          MLb   = (float*)(ws + 45 * MB);
        unsigned short* WoT   = (unsigned short*)(ws + 48 * MB);
        unsigned short* Wop1  = (unsigned short*)(ws);
        unsigned short* Qp    = (unsigned short*)d_out;
        float*          PO    = (float*)d_out;
        float* out = (float*)d_out;

        prep<<<14336, 256, 0, stream>>>(X, Wq, Wk, Wv, Wo, Xbf, WcatT, WoT);
        gemm_qkv<<<768, 256, 0, stream>>>(Xbf, WcatT, Qp, KVp);
        convert_qkv<<<3584, 256, 0, stream>>>(Qp, KVp, cosT, sinT, Qbf, Kbf, Vt);
        attn_mfma<<<dim3(48, HKV_, B_), 256, 0, stream>>>(Qbf, Kbf, Vt,
                                                          Ctxbf, PO, MLb);
        merge_attn<<<2048, 256, 0, stream>>>(PO, MLb, Ctxbf);
        gemm_wo<<<512, 256, 0, stream>>>(Ctxbf, WoT, out, Wop1);
        reduce_wo<<<(M * HID_ / 4) / 256, 256, 0, stream>>>(out, Wop1);
    } else {
        // fallback schedule (ws >= 28 MiB): WoT transposed after merge.
        unsigned short* Xbf   = (unsigned short*)(ws);
        unsigned short* Qbf   = (unsigned short*)(ws);
        unsigned short* WcatT = (unsigned short*)(ws + 8 * MB);
        unsigned short* Kbf   = (unsigned short*)(ws + 8 * MB);
        unsigned short* Vt    = (unsigned short*)(ws + 10 * MB);
        unsigned short* WoT   = (unsigned short*)(ws + 12 * MB);
        float*          MLb   = (float*)(ws + 12 * MB);
        unsigned short* KVp   = (unsigned short*)(ws + 20 * MB);
        unsigned short* Ctxbf = (unsigned short*)(ws + 20 * MB);
        unsigned short* Wop1  = (unsigned short*)(ws);
        unsigned short* Qp    = (unsigned short*)d_out;
        float*          PO    = (float*)d_out;
        float* out = (float*)d_out;

        prep<<<10240, 256, 0, stream>>>(X, Wq, Wk, Wv, Wo, Xbf, WcatT, WoT);
        gemm_qkv<<<768, 256, 0, stream>>>(Xbf, WcatT, Qp, KVp);
        convert_qkv<<<3584, 256, 0, stream>>>(Qp, KVp, cosT, sinT, Qbf, Kbf, Vt);
        attn_mfma<<<dim3(48, HKV_, B_), 256, 0, stream>>>(Qbf, Kbf, Vt,
                                                          Ctxbf, PO, MLb);
        merge_attn<<<2048, 256, 0, stream>>>(PO, MLb, Ctxbf);
        transpose_wo<<<4096, 256, 0, stream>>>(Wo, WoT);
        gemm_wo<<<512, 256, 0, stream>>>(Ctxbf, WoT, out, Wop1);
        reduce_wo<<<(M * HID_ / 4) / 256, 256, 0, stream>>>(out, Wop1);
    }
}